// Round 1
// baseline (69.952 us; speedup 1.0000x reference)
//
#include <hip/hip_runtime.h>
#include <hip/hip_bf16.h>

#define BLOCK 256
#define CHUNK 256           // n-points staged per block (== BLOCK: one stage load/thread)
#define LOG2E 1.44269504088896340736f

// v(p_m) = sum_n exp(-|p_m - g_n|^2) * c_n   (SIGMA = 1)
// Restructure: exp(-|p-g|^2) = exp(-|p|^2) * [exp(-|g|^2)] * exp2(2*log2e * p.g)
//   - exp(-|g|^2) folded into staged controls (once per n per block)
//   - exp(-|p|^2) applied once per thread at the end
// Inner loop: mul, fma (dot), v_exp_f32, fma, fma  + one broadcast ds_read_b128.
__global__ void __launch_bounds__(BLOCK)
translations_kernel(const float* __restrict__ gd,
                    const float* __restrict__ controls,
                    const float* __restrict__ points,
                    float* __restrict__ out,
                    int N, int M) {
    __shared__ float4 sg[CHUNK];

    const int tid = threadIdx.x;
    const int m  = blockIdx.x * BLOCK + tid;
    const int n0 = blockIdx.y * CHUNK;

    // Stage chunk: (gx, gy, c0*exp(-|g|^2), c1*exp(-|g|^2)); zero-pad OOB so the
    // main loop needs no tail handling (w * 0 == 0).
    {
        const int n = n0 + tid;
        if (n < N) {
            float2 g = ((const float2*)gd)[n];
            float2 c = ((const float2*)controls)[n];
            float  e = __expf(-(g.x * g.x + g.y * g.y));
            sg[tid] = make_float4(g.x, g.y, c.x * e, c.y * e);
        } else {
            sg[tid] = make_float4(0.f, 0.f, 0.f, 0.f);
        }
    }
    __syncthreads();

    if (m >= M) return;

    const float2 p  = ((const float2*)points)[m];
    const float  a0 = (2.0f * LOG2E) * p.x;
    const float  a1 = (2.0f * LOG2E) * p.y;

    float acc0 = 0.f, acc1 = 0.f;
#pragma unroll 8
    for (int j = 0; j < CHUNK; ++j) {
        float4 g = sg[j];                       // wave-uniform addr -> LDS broadcast
        float  t = fmaf(a0, g.x, a1 * g.y);     // 2*log2e * (p . g)
        float  w = __builtin_amdgcn_exp2f(t);   // v_exp_f32
        acc0 = fmaf(w, g.z, acc0);
        acc1 = fmaf(w, g.w, acc1);
    }

    const float s = __expf(-(p.x * p.x + p.y * p.y));
    atomicAdd(&out[2 * m],     acc0 * s);
    atomicAdd(&out[2 * m + 1], acc1 * s);
}

extern "C" void kernel_launch(void* const* d_in, const int* in_sizes, int n_in,
                              void* d_out, int out_size, void* d_ws, size_t ws_size,
                              hipStream_t stream) {
    const float* gd       = (const float*)d_in[0];  // [N*2]
    const float* controls = (const float*)d_in[1];  // [N*2]
    const float* points   = (const float*)d_in[2];  // [M,2]
    float* out = (float*)d_out;                     // [M,2] fp32

    const int N = in_sizes[0] / 2;
    const int M = in_sizes[2] / 2;

    // d_out is poisoned with 0xAA before every timed launch; atomics need zeros.
    hipMemsetAsync(d_out, 0, (size_t)out_size * sizeof(float), stream);

    dim3 grid((M + BLOCK - 1) / BLOCK, (N + CHUNK - 1) / CHUNK);
    translations_kernel<<<grid, dim3(BLOCK), 0, stream>>>(gd, controls, points, out, N, M);
}